// Round 2
// baseline (1216.676 us; speedup 1.0000x reference)
//
#include <hip/hip_runtime.h>
#include <stdint.h>

// B=256, K=36 -> 9216 rows; D=2048, E=1024, P=5.
// Pipeline (bf16 MFMA GEMMs, fp32 accumulate, fp32 epilogue math):
//   prep: one merged transpose+cvt dispatch for 5 weights; cvt images to bf16
//   G1: x @ [gate_w1|node_w1] (N=4096) + bias + 0.1*bbox-rank5-corr, relu.
//       gate half: fused dot with gate_w2 -> atomicAdd msum[row] (no store)
//       node half: -> Hn bf16 (9216x2048)
//   G2: Hn @ node_w2 + node_b2 -> V bf16
//   agg: top-P(ballot) gather, m=sigmoid(msum+gb2), out=l2norm(sum m*v), imgs=images+out
//   G3: imgs @ map_w1 + map_b1, relu -> H3 bf16
//   G4: H3 @ map_w2 + map_b2 -> emb fp32 ; final l2norm -> d_out

typedef unsigned short ushort_t;
typedef unsigned int uint32;
typedef __bf16 bf16x8 __attribute__((ext_vector_type(8)));
typedef float f32x4 __attribute__((ext_vector_type(4)));

__device__ __forceinline__ ushort_t f2bf(float f) {
  uint32 u = __float_as_uint(f);
  u += 0x7fffu + ((u >> 16) & 1u);   // RNE
  return (ushort_t)(u >> 16);
}
__device__ __forceinline__ float bflo(uint32 u) { return __uint_as_float(u << 16); }
__device__ __forceinline__ float bfhi(uint32 u) { return __uint_as_float(u & 0xffff0000u); }

__device__ __forceinline__ void gl_lds16(const void* g, void* l) {
  // width-16 async global->LDS; LDS dest is wave-uniform base + lane*16
  __builtin_amdgcn_global_load_lds(
      (__attribute__((address_space(1))) void*)(void*)g,
      (__attribute__((address_space(3))) void*)l, 16, 0, 0);
}

__device__ __forceinline__ float blk_sum(float v, float* sred) {
#pragma unroll
  for (int o = 32; o > 0; o >>= 1) v += __shfl_down(v, o, 64);
  const int w = threadIdx.x >> 6;
  if ((threadIdx.x & 63) == 0) sred[w] = v;
  __syncthreads();
  return sred[0] + sred[1] + sred[2] + sred[3];
}

// ---------- merged transpose + fp32->bf16 for all 5 weight matrices ----------
// src (RKxCN) -> dst (CNxRK). z selects the matrix. RK=2048 always.
__global__ __launch_bounds__(256) void transpose_all(
    const float* __restrict__ gw1, const float* __restrict__ nw1,
    const float* __restrict__ nw2, const float* __restrict__ mw1,
    const float* __restrict__ mw2,
    ushort_t* __restrict__ W1t, ushort_t* __restrict__ W2t,
    ushort_t* __restrict__ W3t, ushort_t* __restrict__ W4t) {
  __shared__ float tile[32][33];
  const float* src;
  ushort_t* dst;
  int CN = 2048;
  switch (blockIdx.z) {
    case 0: src = gw1; dst = W1t; break;
    case 1: src = nw1; dst = W1t + (size_t)2048 * 2048; break;
    case 2: src = nw2; dst = W2t; break;
    case 3: src = mw1; dst = W3t; break;
    default: src = mw2; dst = W4t; CN = 1024; break;
  }
  const int bx = blockIdx.x, by = blockIdx.y;
  if (bx * 32 >= CN) return;
  const int c = bx * 32 + threadIdx.x;
#pragma unroll
  for (int t = 0; t < 4; ++t) {
    int r = by * 32 + threadIdx.y + t * 8;
    tile[threadIdx.y + t * 8][threadIdx.x] = src[(size_t)r * CN + c];
  }
  __syncthreads();
  const int dc = by * 32 + threadIdx.x;  // RK index (contiguous in dst)
#pragma unroll
  for (int t = 0; t < 4; ++t) {
    int dr = bx * 32 + threadIdx.y + t * 8;  // CN index
    dst[(size_t)dr * 2048 + dc] = f2bf(tile[threadIdx.x][threadIdx.y + t * 8]);
  }
}

// ---------- fp32 -> bf16 bulk convert (8 elems/thread) ----------
__global__ __launch_bounds__(256) void cvt_bf16(const float* __restrict__ src,
                                                ushort_t* __restrict__ dst) {
  size_t i = ((size_t)blockIdx.x * 256 + threadIdx.x) * 8;
  float4 a = *(const float4*)(src + i);
  float4 b = *(const float4*)(src + i + 4);
  uint4 o;
  o.x = (uint32)f2bf(a.x) | ((uint32)f2bf(a.y) << 16);
  o.y = (uint32)f2bf(a.z) | ((uint32)f2bf(a.w) << 16);
  o.z = (uint32)f2bf(b.x) | ((uint32)f2bf(b.y) << 16);
  o.w = (uint32)f2bf(b.z) | ((uint32)f2bf(b.w) << 16);
  *(uint4*)(dst + i) = o;
}

// ---------- GEMM: C(M,N) = A(M,K) @ Bt(N,K)^T, bf16 in, fused epilogues ----------
// 128x128 tile, BK=32, 4 waves (2x2 of 64x64), 16x16x32 MFMA, 4x4 acc tiles/wave.
__global__ __launch_bounds__(256) void gemm_bt(
    const ushort_t* __restrict__ A, int lda,
    const ushort_t* __restrict__ Bt, int K,
    void* __restrict__ outp, int ldo, int mode,
    const float* __restrict__ bias,
    const float* __restrict__ gw1, const float* __restrict__ nw1,
    const float* __restrict__ gb1, const float* __restrict__ nb1,
    const float* __restrict__ bboxes,
    const float* __restrict__ gw2, float* __restrict__ msum) {
  __shared__ ushort_t sA[128 * 32];
  __shared__ ushort_t sB[128 * 32];
  const int tid = threadIdx.x;
  const int w = tid >> 6, l = tid & 63;
  const int wm = (w >> 1) * 64, wn = (w & 1) * 64;
  const int lr = l >> 4, lc = l & 15;
  const int mBase = blockIdx.y * 128, cBase = blockIdx.x * 128;

  // staging map: thread t -> row t/4, col8 (t%4)*8 ; LDS offset = t*16B (contiguous)
  const int r0 = tid >> 2;
  const int c8 = (tid & 3) * 8;
  const ushort_t* gA = A + (size_t)(mBase + r0) * lda + c8;
  const ushort_t* gB = Bt + (size_t)(cBase + r0) * K + c8;
  const size_t sA64 = (size_t)64 * lda;
  const size_t sB64 = (size_t)64 * K;
  char* ldsA0 = (char*)sA + w * 1024;          // wave-uniform bases
  char* ldsA1 = (char*)sA + 4096 + w * 1024;
  char* ldsB0 = (char*)sB + w * 1024;
  char* ldsB1 = (char*)sB + 4096 + w * 1024;

  f32x4 acc[4][4] = {};

  for (int k0 = 0; k0 < K; k0 += 32) {
    gl_lds16(gA + k0, ldsA0);
    gl_lds16(gA + sA64 + k0, ldsA1);
    gl_lds16(gB + k0, ldsB0);
    gl_lds16(gB + sB64 + k0, ldsB1);
    __syncthreads();
    bf16x8 af[4], bfr[4];
#pragma unroll
    for (int i = 0; i < 4; ++i)
      af[i] = *(const bf16x8*)&sA[(wm + i * 16 + lc) * 32 + lr * 8];
#pragma unroll
    for (int j = 0; j < 4; ++j)
      bfr[j] = *(const bf16x8*)&sB[(wn + j * 16 + lc) * 32 + lr * 8];
#pragma unroll
    for (int i = 0; i < 4; ++i)
#pragma unroll
      for (int j = 0; j < 4; ++j)
        acc[i][j] = __builtin_amdgcn_mfma_f32_16x16x32_bf16(af[i], bfr[j], acc[i][j], 0, 0, 0);
    __syncthreads();
  }

  // C/D layout: col = lane&15, row = (lane>>4)*4 + e
  if (mode == 1) {
    const bool gate = (cBase < 2048);
    const int coffs = gate ? 0 : 2048;
    const float* b1 = gate ? gb1 : nb1;
    const float* wsrc = gate ? gw1 : nw1;
    float bcol[4], w5[4][5], g2c[4];
#pragma unroll
    for (int j = 0; j < 4; ++j) {
      int c = cBase + wn + j * 16 + lc - coffs;
      bcol[j] = b1[c];
#pragma unroll
      for (int t = 0; t < 5; ++t) w5[j][t] = wsrc[(size_t)(2048 + t) * 2048 + c];
      g2c[j] = gate ? gw2[c] : 0.f;
    }
    if (gate) {
      // h = relu(acc + b + corr); partial = sum_cols h * gw2[col]; butterfly over lc;
      // one atomicAdd per lane into msum[row]
      float rsum[4][4];
#pragma unroll
      for (int i = 0; i < 4; ++i)
#pragma unroll
        for (int e = 0; e < 4; ++e) {
          size_t rg = mBase + wm + i * 16 + lr * 4 + e;
          const float* bb = bboxes + rg * 4;
          float s0 = bb[0], s1 = bb[1], s2 = bb[2], s3 = bb[3];
          float s4 = (s2 - s0) * (s3 - s1);
          float ar = 0.f;
#pragma unroll
          for (int j = 0; j < 4; ++j) {
            float corr = 0.1f * (s0 * w5[j][0] + s1 * w5[j][1] + s2 * w5[j][2] +
                                 s3 * w5[j][3] + s4 * w5[j][4]);
            float v = acc[i][j][e] + bcol[j] + corr;
            v = v > 0.f ? v : 0.f;
            ar += v * g2c[j];
          }
          rsum[i][e] = ar;
        }
#pragma unroll
      for (int m = 1; m < 16; m <<= 1)
#pragma unroll
        for (int i = 0; i < 4; ++i)
#pragma unroll
          for (int e = 0; e < 4; ++e) rsum[i][e] += __shfl_xor(rsum[i][e], m, 64);
      const int ii = lc >> 2, ee = lc & 3;
      atomicAdd(&msum[mBase + wm + ii * 16 + lr * 4 + ee], rsum[ii][ee]);
    } else {
      ushort_t* O = (ushort_t*)outp;
#pragma unroll
      for (int i = 0; i < 4; ++i)
#pragma unroll
        for (int e = 0; e < 4; ++e) {
          size_t rg = mBase + wm + i * 16 + lr * 4 + e;
          const float* bb = bboxes + rg * 4;
          float s0 = bb[0], s1 = bb[1], s2 = bb[2], s3 = bb[3];
          float s4 = (s2 - s0) * (s3 - s1);
#pragma unroll
          for (int j = 0; j < 4; ++j) {
            float corr = 0.1f * (s0 * w5[j][0] + s1 * w5[j][1] + s2 * w5[j][2] +
                                 s3 * w5[j][3] + s4 * w5[j][4]);
            float v = acc[i][j][e] + bcol[j] + corr;
            v = v > 0.f ? v : 0.f;
            O[rg * ldo + (cBase - 2048 + wn + j * 16 + lc)] = f2bf(v);
          }
        }
    }
  } else {
    float bcol[4];
#pragma unroll
    for (int j = 0; j < 4; ++j) bcol[j] = bias[cBase + wn + j * 16 + lc];
    if (mode == 4) {  // fp32 out, no relu
      float* O = (float*)outp;
#pragma unroll
      for (int i = 0; i < 4; ++i)
#pragma unroll
        for (int e = 0; e < 4; ++e) {
          size_t rg = mBase + wm + i * 16 + lr * 4 + e;
#pragma unroll
          for (int j = 0; j < 4; ++j)
            O[rg * ldo + (cBase + wn + j * 16 + lc)] = acc[i][j][e] + bcol[j];
        }
    } else {  // bf16 out; mode 3 applies relu
      const bool do_relu = (mode == 3);
      ushort_t* O = (ushort_t*)outp;
#pragma unroll
      for (int i = 0; i < 4; ++i)
#pragma unroll
        for (int e = 0; e < 4; ++e) {
          size_t rg = mBase + wm + i * 16 + lr * 4 + e;
#pragma unroll
          for (int j = 0; j < 4; ++j) {
            float v = acc[i][j][e] + bcol[j];
            if (do_relu && v < 0.f) v = 0.f;
            O[rg * ldo + (cBase + wn + j * 16 + lc)] = f2bf(v);
          }
        }
    }
  }
}

// ---------- top-P gather + weighted sum + l2norm + residual ----------
__global__ __launch_bounds__(256) void aggregate_k(const float* __restrict__ img_range,
                                                   const float* __restrict__ msum,
                                                   const float* __restrict__ gb2,
                                                   const ushort_t* __restrict__ vbf,
                                                   const float* __restrict__ images,
                                                   ushort_t* __restrict__ imgs_out) {
  __shared__ int s_id[5];
  __shared__ float s_w[5];
  __shared__ float sred[4];
  const int row = blockIdx.x;
  const int b = row / 36, k = row - b * 36;
  const int tid = threadIdx.x;
  if (tid < 64) {  // whole wave 0
    float val = (tid < 36) ? img_range[(size_t)row * 36 + tid] : 0.f;
    unsigned long long mask = __ballot(val == 1.0f);
    if (tid < 5) {
      // tid-th lowest set bit, else self index k  (== jax stable top_k + where)
      unsigned long long mm = mask;
      for (int p = 0; p < tid; ++p) mm &= (mm - 1);
      int id = mm ? (int)__builtin_ctzll(mm) : k;
      s_id[tid] = id;
      s_w[tid] = 1.f / (1.f + expf(-(msum[b * 36 + id] + gb2[0])));
    }
  }
  __syncthreads();
  const int d0 = tid * 8;
  float acc8[8] = {0, 0, 0, 0, 0, 0, 0, 0};
#pragma unroll
  for (int p = 0; p < 5; ++p) {
    uint4 u = *(const uint4*)(vbf + ((size_t)(b * 36 + s_id[p])) * 2048 + d0);
    float wg = s_w[p];
    acc8[0] += wg * bflo(u.x); acc8[1] += wg * bfhi(u.x);
    acc8[2] += wg * bflo(u.y); acc8[3] += wg * bfhi(u.y);
    acc8[4] += wg * bflo(u.z); acc8[5] += wg * bfhi(u.z);
    acc8[6] += wg * bflo(u.w); acc8[7] += wg * bfhi(u.w);
  }
  float ss = 0;
#pragma unroll
  for (int e = 0; e < 8; ++e) ss += acc8[e] * acc8[e];
  float tot = blk_sum(ss, sred);
  float inv = 1.f / (sqrtf(tot) + 1e-8f);
  const float* im = images + (size_t)row * 2048 + d0;
  float4 x0 = *(const float4*)im;
  float4 x1 = *(const float4*)(im + 4);
  float r[8] = {x0.x + acc8[0] * inv, x0.y + acc8[1] * inv, x0.z + acc8[2] * inv,
                x0.w + acc8[3] * inv, x1.x + acc8[4] * inv, x1.y + acc8[5] * inv,
                x1.z + acc8[6] * inv, x1.w + acc8[7] * inv};
  uint4 o;
  o.x = (uint32)f2bf(r[0]) | ((uint32)f2bf(r[1]) << 16);
  o.y = (uint32)f2bf(r[2]) | ((uint32)f2bf(r[3]) << 16);
  o.z = (uint32)f2bf(r[4]) | ((uint32)f2bf(r[5]) << 16);
  o.w = (uint32)f2bf(r[6]) | ((uint32)f2bf(r[7]) << 16);
  *(uint4*)(imgs_out + (size_t)row * 2048 + d0) = o;
}

// ---------- final l2norm over E=1024 ----------
__global__ __launch_bounds__(256) void l2norm_k(const float* __restrict__ emb,
                                                float* __restrict__ out) {
  __shared__ float sred[4];
  size_t base = (size_t)blockIdx.x * 1024 + threadIdx.x * 4;
  float4 x = *(const float4*)(emb + base);
  float tot = blk_sum(x.x * x.x + x.y * x.y + x.z * x.z + x.w * x.w, sred);
  float inv = 1.f / (sqrtf(tot) + 1e-8f);
  float4 o = {x.x * inv, x.y * inv, x.z * inv, x.w * inv};
  *(float4*)(out + base) = o;
}

extern "C" void kernel_launch(void* const* d_in, const int* in_sizes, int n_in,
                              void* d_out, int out_size, void* d_ws, size_t ws_size,
                              hipStream_t stream) {
  (void)in_sizes; (void)n_in; (void)out_size; (void)ws_size;
  const float* images    = (const float*)d_in[0];
  const float* bboxes    = (const float*)d_in[1];
  const float* img_range = (const float*)d_in[2];
  const float* gate_w1   = (const float*)d_in[3];
  const float* gate_b1   = (const float*)d_in[4];
  const float* gate_w2   = (const float*)d_in[5];
  const float* gate_b2   = (const float*)d_in[6];
  const float* node_w1   = (const float*)d_in[7];
  const float* node_b1   = (const float*)d_in[8];
  const float* node_w2   = (const float*)d_in[9];
  const float* node_b2   = (const float*)d_in[10];
  const float* map_w1    = (const float*)d_in[11];
  const float* map_b1    = (const float*)d_in[12];
  const float* map_w2    = (const float*)d_in[13];
  const float* map_b2    = (const float*)d_in[14];

  char* ws = (char*)d_ws;
  size_t off = 0;
  auto take = [&](size_t bytes) {
    char* p = ws + off;
    off += (bytes + 255) & ~(size_t)255;
    return p;
  };
  ushort_t* W1t  = (ushort_t*)take((size_t)4096 * 2048 * 2);  // [gate|node]_w1^T
  ushort_t* W2t  = (ushort_t*)take((size_t)2048 * 2048 * 2);  // node_w2^T
  ushort_t* W3t  = (ushort_t*)take((size_t)2048 * 2048 * 2);  // map_w1^T
  ushort_t* W4t  = (ushort_t*)take((size_t)1024 * 2048 * 2);  // map_w2^T
  ushort_t* Abuf = (ushort_t*)take((size_t)9216 * 2048 * 2);  // images_bf16 -> imgs_bf16
  ushort_t* Hn   = (ushort_t*)take((size_t)9216 * 2048 * 2);  // node hidden -> H3
  ushort_t* Vbuf = (ushort_t*)take((size_t)9216 * 2048 * 2);  // V bf16 -> Emb fp32
  float*    Msum = (float*)take((size_t)9216 * 4);
  float*    Emb  = (float*)Vbuf;                              // 9216*1024 fp32 = same bytes

  hipMemsetAsync(Msum, 0, (size_t)9216 * 4, stream);
  transpose_all<<<dim3(64, 64, 5), dim3(32, 8), 0, stream>>>(
      gate_w1, node_w1, node_w2, map_w1, map_w2, W1t, W2t, W3t, W4t);
  cvt_bf16<<<9216, 256, 0, stream>>>(images, Abuf);

  // G1: (9216 x 2048) @ (2048 x 4096); gate half -> msum atomics, node half -> Hn
  gemm_bt<<<dim3(32, 72), 256, 0, stream>>>(Abuf, 2048, W1t, 2048, Hn, 2048, 1,
                                            nullptr, gate_w1, node_w1, gate_b1, node_b1,
                                            bboxes, gate_w2, Msum);
  // G2: Hn @ node_w2 + node_b2 -> V
  gemm_bt<<<dim3(16, 72), 256, 0, stream>>>(Hn, 2048, W2t, 2048, Vbuf, 2048, 2,
                                            node_b2, nullptr, nullptr, nullptr, nullptr,
                                            nullptr, nullptr, nullptr);
  aggregate_k<<<9216, 256, 0, stream>>>(img_range, Msum, gate_b2, Vbuf, images, Abuf);
  // G3: imgs @ map_w1 + map_b1, relu -> H3 (reuse Hn)
  gemm_bt<<<dim3(16, 72), 256, 0, stream>>>(Abuf, 2048, W3t, 2048, Hn, 2048, 3,
                                            map_b1, nullptr, nullptr, nullptr, nullptr,
                                            nullptr, nullptr, nullptr);
  // G4: H3 @ map_w2 + map_b2 -> emb fp32 (reuse Vbuf)
  gemm_bt<<<dim3(8, 72), 256, 0, stream>>>(Hn, 2048, W4t, 2048, Emb, 1024, 4,
                                           map_b2, nullptr, nullptr, nullptr, nullptr,
                                           nullptr, nullptr, nullptr);
  l2norm_k<<<9216, 256, 0, stream>>>(Emb, (float*)d_out);
}

// Round 3
// 744.770 us; speedup vs baseline: 1.6336x; 1.6336x over previous
//
#include <hip/hip_runtime.h>
#include <stdint.h>

// B=256, K=36 -> 9216 rows; D=2048, E=1024, P=5.
// Pipeline (bf16 MFMA GEMMs, fp32 accumulate):
//   transpose_all: 5 weight matrices -> B^T bf16 (W1^T zero-padded K 2053->2080)
//   build_A: A = [images | 0.1*s_infos | 0pad] bf16, 9216 x 2080
//   G1: A @ W1t (K=2080, N=4096) + bias, relu -> Hcat bf16   [pure GEMM epilogue]
//   gate2: m = sigmoid(Hcat[:, :2048] . gate_w2 + gate_b2)
//   G2: Hcat[:,2048:] @ node_w2 + node_b2 -> V bf16
//   agg: top-P(ballot) gather, out=l2norm(sum m*v), imgs=images+out -> bf16
//   G3: imgs @ map_w1 + map_b1, relu -> H3 bf16 (into Hcat)
//   G4: H3 @ map_w2 + map_b2 -> emb fp32 ; final l2norm -> d_out
// NOTE: gemm is TEMPLATED per epilogue — round 2 showed a mode-switched
// mega-kernel takes worst-case VGPR (152) and halves occupancy for all modes.

typedef unsigned short ushort_t;
typedef unsigned int uint32;
typedef __bf16 bf16x8 __attribute__((ext_vector_type(8)));
typedef float f32x4 __attribute__((ext_vector_type(4)));

__device__ __forceinline__ ushort_t f2bf(float f) {
  uint32 u = __float_as_uint(f);
  u += 0x7fffu + ((u >> 16) & 1u);   // RNE
  return (ushort_t)(u >> 16);
}
__device__ __forceinline__ float bflo(uint32 u) { return __uint_as_float(u << 16); }
__device__ __forceinline__ float bfhi(uint32 u) { return __uint_as_float(u & 0xffff0000u); }

__device__ __forceinline__ void gl_lds16(const void* g, void* l) {
  __builtin_amdgcn_global_load_lds(
      (__attribute__((address_space(1))) void*)(void*)g,
      (__attribute__((address_space(3))) void*)l, 16, 0, 0);
}

__device__ __forceinline__ float blk_sum(float v, float* sred) {
#pragma unroll
  for (int o = 32; o > 0; o >>= 1) v += __shfl_down(v, o, 64);
  const int w = threadIdx.x >> 6;
  if ((threadIdx.x & 63) == 0) sred[w] = v;
  __syncthreads();
  return sred[0] + sred[1] + sred[2] + sred[3];
}

// ---------- merged transpose + fp32->bf16 for all 5 weight matrices ----------
// src (RKsrc x CN) -> dst (CN x RKdst), rows >= RKsrc zero-filled.
__global__ __launch_bounds__(256) void transpose_all(
    const float* __restrict__ gw1, const float* __restrict__ nw1,
    const float* __restrict__ nw2, const float* __restrict__ mw1,
    const float* __restrict__ mw2,
    ushort_t* __restrict__ W1t, ushort_t* __restrict__ W2t,
    ushort_t* __restrict__ W3t, ushort_t* __restrict__ W4t) {
  __shared__ float tile[32][33];
  const float* src;
  ushort_t* dst;
  int RKsrc, RKdst, CN;
  switch (blockIdx.z) {
    case 0: src = gw1; dst = W1t;                        RKsrc = 2053; RKdst = 2080; CN = 2048; break;
    case 1: src = nw1; dst = W1t + (size_t)2048 * 2080;  RKsrc = 2053; RKdst = 2080; CN = 2048; break;
    case 2: src = nw2; dst = W2t;                        RKsrc = 2048; RKdst = 2048; CN = 2048; break;
    case 3: src = mw1; dst = W3t;                        RKsrc = 2048; RKdst = 2048; CN = 2048; break;
    default: src = mw2; dst = W4t;                       RKsrc = 2048; RKdst = 2048; CN = 1024; break;
  }
  const int bx = blockIdx.x, by = blockIdx.y;
  if (bx * 32 >= CN || by * 32 >= RKdst) return;
  const int c = bx * 32 + threadIdx.x;
#pragma unroll
  for (int t = 0; t < 4; ++t) {
    int r = by * 32 + threadIdx.y + t * 8;
    tile[threadIdx.y + t * 8][threadIdx.x] = (r < RKsrc) ? src[(size_t)r * CN + c] : 0.f;
  }
  __syncthreads();
  const int dc = by * 32 + threadIdx.x;  // K index (contiguous in dst)
#pragma unroll
  for (int t = 0; t < 4; ++t) {
    int dr = bx * 32 + threadIdx.y + t * 8;  // CN index
    dst[(size_t)dr * RKdst + dc] = f2bf(tile[threadIdx.x][threadIdx.y + t * 8]);
  }
}

// ---------- build A = [images_bf16 | 0.1*s_infos | 0] (9216 x 2080) ----------
__global__ __launch_bounds__(256) void build_A(const float* __restrict__ images,
                                               const float* __restrict__ bboxes,
                                               ushort_t* __restrict__ A) {
  const int row = blockIdx.x, tid = threadIdx.x;
  size_t i = (size_t)row * 2048 + tid * 8;
  float4 a = *(const float4*)(images + i);
  float4 b = *(const float4*)(images + i + 4);
  uint4 o;
  o.x = (uint32)f2bf(a.x) | ((uint32)f2bf(a.y) << 16);
  o.y = (uint32)f2bf(a.z) | ((uint32)f2bf(a.w) << 16);
  o.z = (uint32)f2bf(b.x) | ((uint32)f2bf(b.y) << 16);
  o.w = (uint32)f2bf(b.z) | ((uint32)f2bf(b.w) << 16);
  *(uint4*)(A + (size_t)row * 2080 + tid * 8) = o;
  if (tid < 4) {
    uint4 s = {0, 0, 0, 0};
    if (tid == 0) {
      const float* bb = bboxes + (size_t)row * 4;
      float s0 = bb[0], s1 = bb[1], s2 = bb[2], s3 = bb[3];
      float s4 = (s2 - s0) * (s3 - s1);
      s.x = (uint32)f2bf(0.1f * s0) | ((uint32)f2bf(0.1f * s1) << 16);
      s.y = (uint32)f2bf(0.1f * s2) | ((uint32)f2bf(0.1f * s3) << 16);
      s.z = (uint32)f2bf(0.1f * s4);
    }
    *(uint4*)(A + (size_t)row * 2080 + 2048 + tid * 8) = s;
  }
}

// ---------- GEMM: C(M,N) = A(M,K) @ Bt(N,K)^T, bf16 in, fp32 acc ----------
// 128x128 tile, BK=32, 4 waves (2x2 of 64x64), 16x16x32 MFMA, 4x4 acc/wave.
// MODE 0: bias+relu -> bf16 ; MODE 1: bias -> bf16 ; MODE 2: bias -> fp32
template <int MODE>
__global__ __launch_bounds__(256) void gemm_bt(
    const ushort_t* __restrict__ A, int lda,
    const ushort_t* __restrict__ Bt, int K,
    void* __restrict__ outp, int ldo,
    const float* __restrict__ bias, const float* __restrict__ bias2, int nsplit) {
  __shared__ ushort_t sA[128 * 32];
  __shared__ ushort_t sB[128 * 32];
  const int tid = threadIdx.x;
  const int w = tid >> 6, l = tid & 63;
  const int wm = (w >> 1) * 64, wn = (w & 1) * 64;
  const int lr = l >> 4, lc = l & 15;
  const int mBase = blockIdx.y * 128, cBase = blockIdx.x * 128;

  const int r0 = tid >> 2;
  const int c8 = (tid & 3) * 8;
  const ushort_t* gA = A + (size_t)(mBase + r0) * lda + c8;
  const ushort_t* gB = Bt + (size_t)(cBase + r0) * K + c8;
  const size_t sA64 = (size_t)64 * lda;
  const size_t sB64 = (size_t)64 * K;
  char* ldsA0 = (char*)sA + w * 1024;
  char* ldsA1 = (char*)sA + 4096 + w * 1024;
  char* ldsB0 = (char*)sB + w * 1024;
  char* ldsB1 = (char*)sB + 4096 + w * 1024;

  f32x4 acc[4][4] = {};

  for (int k0 = 0; k0 < K; k0 += 32) {
    gl_lds16(gA + k0, ldsA0);
    gl_lds16(gA + sA64 + k0, ldsA1);
    gl_lds16(gB + k0, ldsB0);
    gl_lds16(gB + sB64 + k0, ldsB1);
    __syncthreads();
    bf16x8 af[4], bfr[4];
#pragma unroll
    for (int i = 0; i < 4; ++i)
      af[i] = *(const bf16x8*)&sA[(wm + i * 16 + lc) * 32 + lr * 8];
#pragma unroll
    for (int j = 0; j < 4; ++j)
      bfr[j] = *(const bf16x8*)&sB[(wn + j * 16 + lc) * 32 + lr * 8];
#pragma unroll
    for (int i = 0; i < 4; ++i)
#pragma unroll
      for (int j = 0; j < 4; ++j)
        acc[i][j] = __builtin_amdgcn_mfma_f32_16x16x32_bf16(af[i], bfr[j], acc[i][j], 0, 0, 0);
    __syncthreads();
  }

  // C/D layout: col = lane&15, row = (lane>>4)*4 + e
  const float* bp = (cBase < nsplit) ? bias : bias2;
  const int cof = (cBase < nsplit) ? 0 : nsplit;
  float bcol[4];
#pragma unroll
  for (int j = 0; j < 4; ++j) bcol[j] = bp[cBase + wn + j * 16 + lc - cof];
#pragma unroll
  for (int i = 0; i < 4; ++i)
#pragma unroll
    for (int e = 0; e < 4; ++e) {
      size_t rg = mBase + wm + i * 16 + lr * 4 + e;
#pragma unroll
      for (int j = 0; j < 4; ++j) {
        float v = acc[i][j][e] + bcol[j];
        if (MODE == 0 && v < 0.f) v = 0.f;
        size_t oi = rg * ldo + (cBase + wn + j * 16 + lc);
        if (MODE == 2) ((float*)outp)[oi] = v;
        else ((ushort_t*)outp)[oi] = f2bf(v);
      }
    }
}

// ---------- gate layer 2: m = sigmoid(h_gate . gw2 + gb2) ----------
__global__ __launch_bounds__(256) void gate2_k(const ushort_t* __restrict__ hcat,
                                               const float* __restrict__ gw2,
                                               const float* __restrict__ gb2,
                                               float* __restrict__ msig) {
  __shared__ float sred[4];
  const int row = blockIdx.x;
  const int d0 = threadIdx.x * 8;  // 256*8 = 2048
  uint4 u = *(const uint4*)(hcat + (size_t)row * 4096 + d0);
  float4 w0 = *(const float4*)(gw2 + d0);
  float4 w1 = *(const float4*)(gw2 + d0 + 4);
  float s = bflo(u.x) * w0.x + bfhi(u.x) * w0.y + bflo(u.y) * w0.z + bfhi(u.y) * w0.w +
            bflo(u.z) * w1.x + bfhi(u.z) * w1.y + bflo(u.w) * w1.z + bfhi(u.w) * w1.w;
  float tot = blk_sum(s, sred);
  if (threadIdx.x == 0) msig[row] = 1.f / (1.f + expf(-(tot + gb2[0])));
}

// ---------- top-P gather + weighted sum + l2norm + residual ----------
__global__ __launch_bounds__(256) void aggregate_k(const float* __restrict__ img_range,
                                                   const float* __restrict__ msig,
                                                   const ushort_t* __restrict__ vbf,
                                                   const float* __restrict__ images,
                                                   ushort_t* __restrict__ imgs_out) {
  __shared__ int s_id[5];
  __shared__ float s_w[5];
  __shared__ float sred[4];
  const int row = blockIdx.x;
  const int b = row / 36, k = row - b * 36;
  const int tid = threadIdx.x;
  if (tid < 64) {  // whole wave 0
    float val = (tid < 36) ? img_range[(size_t)row * 36 + tid] : 0.f;
    unsigned long long mask = __ballot(val == 1.0f);
    if (tid < 5) {
      // tid-th lowest set bit, else self index k  (== jax stable top_k + where)
      unsigned long long mm = mask;
      for (int p = 0; p < tid; ++p) mm &= (mm - 1);
      int id = mm ? (int)__builtin_ctzll(mm) : k;
      s_id[tid] = id;
      s_w[tid] = msig[b * 36 + id];
    }
  }
  __syncthreads();
  const int d0 = tid * 8;
  float acc8[8] = {0, 0, 0, 0, 0, 0, 0, 0};
#pragma unroll
  for (int p = 0; p < 5; ++p) {
    uint4 u = *(const uint4*)(vbf + ((size_t)(b * 36 + s_id[p])) * 2048 + d0);
    float wg = s_w[p];
    acc8[0] += wg * bflo(u.x); acc8[1] += wg * bfhi(u.x);
    acc8[2] += wg * bflo(u.y); acc8[3] += wg * bfhi(u.y);
    acc8[4] += wg * bflo(u.z); acc8[5] += wg * bfhi(u.z);
    acc8[6] += wg * bflo(u.w); acc8[7] += wg * bfhi(u.w);
  }
  float ss = 0;
#pragma unroll
  for (int e = 0; e < 8; ++e) ss += acc8[e] * acc8[e];
  float tot = blk_sum(ss, sred);
  float inv = 1.f / (sqrtf(tot) + 1e-8f);
  const float* im = images + (size_t)row * 2048 + d0;
  float4 x0 = *(const float4*)im;
  float4 x1 = *(const float4*)(im + 4);
  float r[8] = {x0.x + acc8[0] * inv, x0.y + acc8[1] * inv, x0.z + acc8[2] * inv,
                x0.w + acc8[3] * inv, x1.x + acc8[4] * inv, x1.y + acc8[5] * inv,
                x1.z + acc8[6] * inv, x1.w + acc8[7] * inv};
  uint4 o;
  o.x = (uint32)f2bf(r[0]) | ((uint32)f2bf(r[1]) << 16);
  o.y = (uint32)f2bf(r[2]) | ((uint32)f2bf(r[3]) << 16);
  o.z = (uint32)f2bf(r[4]) | ((uint32)f2bf(r[5]) << 16);
  o.w = (uint32)f2bf(r[6]) | ((uint32)f2bf(r[7]) << 16);
  *(uint4*)(imgs_out + (size_t)row * 2048 + d0) = o;
}

// ---------- final l2norm over E=1024 ----------
__global__ __launch_bounds__(256) void l2norm_k(const float* __restrict__ emb,
                                                float* __restrict__ out) {
  __shared__ float sred[4];
  size_t base = (size_t)blockIdx.x * 1024 + threadIdx.x * 4;
  float4 x = *(const float4*)(emb + base);
  float tot = blk_sum(x.x * x.x + x.y * x.y + x.z * x.z + x.w * x.w, sred);
  float inv = 1.f / (sqrtf(tot) + 1e-8f);
  float4 o = {x.x * inv, x.y * inv, x.z * inv, x.w * inv};
  *(float4*)(out + base) = o;
}

extern "C" void kernel_launch(void* const* d_in, const int* in_sizes, int n_in,
                              void* d_out, int out_size, void* d_ws, size_t ws_size,
                              hipStream_t stream) {
  (void)in_sizes; (void)n_in; (void)out_size; (void)ws_size;
  const float* images    = (const float*)d_in[0];
  const float* bboxes    = (const float*)d_in[1];
  const float* img_range = (const float*)d_in[2];
  const float* gate_w1   = (const float*)d_in[3];
  const float* gate_b1   = (const float*)d_in[4];
  const float* gate_w2   = (const float*)d_in[5];
  const float* gate_b2   = (const float*)d_in[6];
  const float* node_w1   = (const float*)d_in[7];
  const float* node_b1   = (const float*)d_in[8];
  const float* node_w2   = (const float*)d_in[9];
  const float* node_b2   = (const float*)d_in[10];
  const float* map_w1    = (const float*)d_in[11];
  const float* map_b1    = (const float*)d_in[12];
  const float* map_w2    = (const float*)d_in[13];
  const float* map_b2    = (const float*)d_in[14];

  char* ws = (char*)d_ws;
  size_t off = 0;
  auto take = [&](size_t bytes) {
    char* p = ws + off;
    off += (bytes + 255) & ~(size_t)255;
    return p;
  };
  ushort_t* W1t  = (ushort_t*)take((size_t)4096 * 2080 * 2);  // [gate|node]_w1^T, K-padded
  ushort_t* W2t  = (ushort_t*)take((size_t)2048 * 2048 * 2);  // node_w2^T
  ushort_t* W3t  = (ushort_t*)take((size_t)2048 * 2048 * 2);  // map_w1^T
  ushort_t* W4t  = (ushort_t*)take((size_t)1024 * 2048 * 2);  // map_w2^T
  ushort_t* Abuf = (ushort_t*)take((size_t)9216 * 2080 * 2);  // A -> imgs bf16 (2048-wide)
  ushort_t* Hcat = (ushort_t*)take((size_t)9216 * 4096 * 2);  // [gate|node] hidden -> H3
  ushort_t* Vbuf = (ushort_t*)take((size_t)9216 * 2048 * 2);  // V bf16 -> Emb fp32
  float*    Msig = (float*)take((size_t)9216 * 4);
  float*    Emb  = (float*)Vbuf;  // 9216*1024 fp32 == same bytes

  transpose_all<<<dim3(64, 65, 5), dim3(32, 8), 0, stream>>>(
      gate_w1, node_w1, node_w2, map_w1, map_w2, W1t, W2t, W3t, W4t);
  build_A<<<9216, 256, 0, stream>>>(images, bboxes, Abuf);

  // G1: (9216 x 2080) @ (2080 x 4096) + [gate_b1|node_b1], relu -> Hcat
  gemm_bt<0><<<dim3(32, 72), 256, 0, stream>>>(Abuf, 2080, W1t, 2080, Hcat, 4096,
                                               gate_b1, node_b1, 2048);
  gate2_k<<<9216, 256, 0, stream>>>(Hcat, gate_w2, gate_b2, Msig);
  // G2: node hidden @ node_w2 + node_b2 -> V
  gemm_bt<1><<<dim3(16, 72), 256, 0, stream>>>(Hcat + 2048, 4096, W2t, 2048, Vbuf, 2048,
                                               node_b2, node_b2, 1 << 30);
  aggregate_k<<<9216, 256, 0, stream>>>(img_range, Msig, Vbuf, images, Abuf);
  // G3: imgs @ map_w1 + map_b1, relu -> H3 (into Hcat, 2048-wide)
  gemm_bt<0><<<dim3(16, 72), 256, 0, stream>>>(Abuf, 2048, W3t, 2048, Hcat, 2048,
                                               map_b1, map_b1, 1 << 30);
  // G4: H3 @ map_w2 + map_b2 -> emb fp32 (into Vbuf)
  gemm_bt<2><<<dim3(8, 72), 256, 0, stream>>>(Hcat, 2048, W4t, 2048, Emb, 1024,
                                              map_b2, map_b2, 1 << 30);
  l2norm_k<<<9216, 256, 0, stream>>>(Emb, (float*)d_out);
}

// Round 4
// 727.444 us; speedup vs baseline: 1.6725x; 1.0238x over previous
//
#include <hip/hip_runtime.h>
#include <stdint.h>

// B=256, K=36 -> 9216 rows; D=2048, E=1024, P=5.
// Pipeline (bf16 MFMA GEMMs, fp32 accumulate):
//   prep_k: 5 weight transposes (W1^T K-padded 2053->2112) + A=[img|0.1*s|0] in ONE dispatch
//   Gn: A @ node_w1^T (K=2112) + node_b1, relu -> Hn bf16            [gemm_bt<0>]
//   Gg: A @ gate_w1^T, fused epilogue relu(h).gw2 -> Gpart(9216x32)  [gemm_gate]
//   G2: Hn @ node_w2^T + node_b2 -> V bf16                           [gemm_bt<1>]
//   agg: m=sigmoid(sum Gpart + gb2); top-P ballot gather; imgs=images+l2norm(sum m*v)
//   G3: imgs @ map_w1^T + map_b1, relu -> H3 (into Hn)               [gemm_bt<0>]
//   G4: H3 @ map_w2^T + map_b2 -> Emb fp32                           [gemm_bt<2>]
//   l2norm -> d_out
// GEMM core: 128x128 tile, BK=64 as TWO sequential BK=32 sub-tiles (identical
// LDS banking to the known-good BK=32 layout; 32 MFMA per barrier, halved drains).
// Templated per epilogue — r2 showed mode-switched mega-kernel takes worst-case VGPR.

typedef unsigned short ushort_t;
typedef unsigned int uint32;
typedef __bf16 bf16x8 __attribute__((ext_vector_type(8)));
typedef float f32x4 __attribute__((ext_vector_type(4)));

__device__ __forceinline__ ushort_t f2bf(float f) {
  uint32 u = __float_as_uint(f);
  u += 0x7fffu + ((u >> 16) & 1u);   // RNE
  return (ushort_t)(u >> 16);
}
__device__ __forceinline__ float bflo(uint32 u) { return __uint_as_float(u << 16); }
__device__ __forceinline__ float bfhi(uint32 u) { return __uint_as_float(u & 0xffff0000u); }

__device__ __forceinline__ void gl_lds16(const void* g, void* l) {
  __builtin_amdgcn_global_load_lds(
      (__attribute__((address_space(1))) void*)(void*)g,
      (__attribute__((address_space(3))) void*)l, 16, 0, 0);
}

__device__ __forceinline__ float blk_sum(float v, float* sred) {
#pragma unroll
  for (int o = 32; o > 0; o >>= 1) v += __shfl_down(v, o, 64);
  const int w = threadIdx.x >> 6;
  if ((threadIdx.x & 63) == 0) sred[w] = v;
  __syncthreads();
  return sred[0] + sred[1] + sred[2] + sred[3];
}

// ---------- prep: 5 weight transposes (z=0..4) + build_A (z=5,6) ----------
__global__ __launch_bounds__(256) void prep_k(
    const float* __restrict__ gw1, const float* __restrict__ nw1,
    const float* __restrict__ nw2, const float* __restrict__ mw1,
    const float* __restrict__ mw2,
    const float* __restrict__ images, const float* __restrict__ bboxes,
    ushort_t* __restrict__ W1t, ushort_t* __restrict__ W2t,
    ushort_t* __restrict__ W3t, ushort_t* __restrict__ W4t,
    ushort_t* __restrict__ Abuf) {
  __shared__ float tile[32][33];
  const int z = blockIdx.z;
  if (z >= 5) {
    // build A = [images_bf16 | 0.1*s_infos | 0pad], 2112 wide; one row per block
    const int tid = threadIdx.y * 32 + threadIdx.x;
    const int row = (z - 5) * 4608 + blockIdx.y * 64 + blockIdx.x;
    size_t i = (size_t)row * 2048 + tid * 8;
    float4 a = *(const float4*)(images + i);
    float4 b = *(const float4*)(images + i + 4);
    uint4 o;
    o.x = (uint32)f2bf(a.x) | ((uint32)f2bf(a.y) << 16);
    o.y = (uint32)f2bf(a.z) | ((uint32)f2bf(a.w) << 16);
    o.z = (uint32)f2bf(b.x) | ((uint32)f2bf(b.y) << 16);
    o.w = (uint32)f2bf(b.z) | ((uint32)f2bf(b.w) << 16);
    *(uint4*)(Abuf + (size_t)row * 2112 + tid * 8) = o;
    if (tid < 8) {
      uint4 s = {0, 0, 0, 0};
      if (tid == 0) {
        const float* bb = bboxes + (size_t)row * 4;
        float s0 = bb[0], s1 = bb[1], s2 = bb[2], s3 = bb[3];
        float s4 = (s2 - s0) * (s3 - s1);
        s.x = (uint32)f2bf(0.1f * s0) | ((uint32)f2bf(0.1f * s1) << 16);
        s.y = (uint32)f2bf(0.1f * s2) | ((uint32)f2bf(0.1f * s3) << 16);
        s.z = (uint32)f2bf(0.1f * s4);
      }
      *(uint4*)(Abuf + (size_t)row * 2112 + 2048 + tid * 8) = s;
    }
    return;
  }
  // transpose src (RKsrc x CN) -> dst (CN x RKdst), rows >= RKsrc zero-filled
  const float* src;
  ushort_t* dst;
  int RKsrc, RKdst, CN;
  switch (z) {
    case 0: src = gw1; dst = W1t;                        RKsrc = 2053; RKdst = 2112; CN = 2048; break;
    case 1: src = nw1; dst = W1t + (size_t)2048 * 2112;  RKsrc = 2053; RKdst = 2112; CN = 2048; break;
    case 2: src = nw2; dst = W2t;                        RKsrc = 2048; RKdst = 2048; CN = 2048; break;
    case 3: src = mw1; dst = W3t;                        RKsrc = 2048; RKdst = 2048; CN = 2048; break;
    default: src = mw2; dst = W4t;                       RKsrc = 2048; RKdst = 2048; CN = 1024; break;
  }
  const int bx = blockIdx.x, by = blockIdx.y;
  if (bx * 32 >= CN || by * 32 >= RKdst) return;
  const int c = bx * 32 + threadIdx.x;
#pragma unroll
  for (int t = 0; t < 4; ++t) {
    int r = by * 32 + threadIdx.y + t * 8;
    tile[threadIdx.y + t * 8][threadIdx.x] = (r < RKsrc) ? src[(size_t)r * CN + c] : 0.f;
  }
  __syncthreads();
  const int dc = by * 32 + threadIdx.x;  // K index (contiguous in dst)
#pragma unroll
  for (int t = 0; t < 4; ++t) {
    int dr = bx * 32 + threadIdx.y + t * 8;  // CN index
    dst[(size_t)dr * RKdst + dc] = f2bf(tile[threadIdx.x][threadIdx.y + t * 8]);
  }
}

// ---------- GEMM core (BK=64 = 2x BK=32 sub-tiles), shared by all variants ----------
#define GEMM_CORE(A, lda, Bt, K)                                                \
  __shared__ ushort_t sA[2 * 128 * 32];                                         \
  __shared__ ushort_t sB[2 * 128 * 32];                                         \
  const int tid = threadIdx.x;                                                  \
  const int w = tid >> 6, l = tid & 63;                                         \
  const int wm = (w >> 1) * 64, wn = (w & 1) * 64;                              \
  const int lr = l >> 4, lc = l & 15;                                           \
  const int mBase = blockIdx.y * 128, cBase = blockIdx.x * 128;                 \
  const int r0 = tid >> 2, c8 = (tid & 3) * 8;                                  \
  const ushort_t* gA = (A) + (size_t)(mBase + r0) * (lda) + c8;                 \
  const ushort_t* gB = (Bt) + (size_t)(cBase + r0) * (K) + c8;                  \
  const size_t sA64 = (size_t)64 * (lda), sB64 = (size_t)64 * (K);              \
  char* lA = (char*)sA + w * 1024;                                              \
  char* lB = (char*)sB + w * 1024;                                              \
  f32x4 acc[4][4] = {};                                                         \
  for (int k0 = 0; k0 < (K); k0 += 64) {                                        \
    gl_lds16(gA + k0, lA);                                                      \
    gl_lds16(gA + sA64 + k0, lA + 4096);                                        \
    gl_lds16(gA + k0 + 32, lA + 8192);                                          \
    gl_lds16(gA + sA64 + k0 + 32, lA + 12288);                                  \
    gl_lds16(gB + k0, lB);                                                      \
    gl_lds16(gB + sB64 + k0, lB + 4096);                                        \
    gl_lds16(gB + k0 + 32, lB + 8192);                                          \
    gl_lds16(gB + sB64 + k0 + 32, lB + 12288);                                  \
    __syncthreads();                                                            \
    _Pragma("unroll")                                                           \
    for (int kk = 0; kk < 2; ++kk) {                                            \
      const ushort_t* pA = sA + kk * 4096;                                      \
      const ushort_t* pB = sB + kk * 4096;                                      \
      bf16x8 af[4], bfr[4];                                                     \
      _Pragma("unroll")                                                         \
      for (int i = 0; i < 4; ++i)                                               \
        af[i] = *(const bf16x8*)&pA[(wm + i * 16 + lc) * 32 + lr * 8];          \
      _Pragma("unroll")                                                         \
      for (int j = 0; j < 4; ++j)                                               \
        bfr[j] = *(const bf16x8*)&pB[(wn + j * 16 + lc) * 32 + lr * 8];         \
      _Pragma("unroll")                                                         \
      for (int i = 0; i < 4; ++i)                                               \
        _Pragma("unroll")                                                       \
        for (int j = 0; j < 4; ++j)                                             \
          acc[i][j] = __builtin_amdgcn_mfma_f32_16x16x32_bf16(af[i], bfr[j],    \
                                                              acc[i][j], 0, 0, 0); \
    }                                                                           \
    __syncthreads();                                                            \
  }

// C/D layout: col = lane&15, row = (lane>>4)*4 + e
// MODE 0: bias+relu -> bf16 ; MODE 1: bias -> bf16 ; MODE 2: bias -> fp32
template <int MODE>
__global__ __launch_bounds__(256) void gemm_bt(
    const ushort_t* __restrict__ A, int lda,
    const ushort_t* __restrict__ Bt, int K,
    void* __restrict__ outp, int ldo, const float* __restrict__ bias) {
  GEMM_CORE(A, lda, Bt, K)
  float bcol[4];
#pragma unroll
  for (int j = 0; j < 4; ++j) bcol[j] = bias[cBase + wn + j * 16 + lc];
#pragma unroll
  for (int i = 0; i < 4; ++i)
#pragma unroll
    for (int e = 0; e < 4; ++e) {
      size_t rg = mBase + wm + i * 16 + lr * 4 + e;
#pragma unroll
      for (int j = 0; j < 4; ++j) {
        float v = acc[i][j][e] + bcol[j];
        if (MODE == 0 && v < 0.f) v = 0.f;
        size_t oi = rg * ldo + (cBase + wn + j * 16 + lc);
        if (MODE == 2) ((float*)outp)[oi] = v;
        else ((ushort_t*)outp)[oi] = f2bf(v);
      }
    }
}

// gate GEMM: epilogue computes sum_col relu(h)*gw2[col] partials -> Gpart[row][32]
__global__ __launch_bounds__(256) void gemm_gate(
    const ushort_t* __restrict__ A, int lda,
    const ushort_t* __restrict__ Bt, int K,
    const float* __restrict__ bias, const float* __restrict__ gw2,
    float* __restrict__ Gpart) {
  GEMM_CORE(A, lda, Bt, K)
  float bcol[4], g2c[4];
#pragma unroll
  for (int j = 0; j < 4; ++j) {
    int c = cBase + wn + j * 16 + lc;
    bcol[j] = bias[c];
    g2c[j] = gw2[c];
  }
  float rsum[4][4];
#pragma unroll
  for (int i = 0; i < 4; ++i)
#pragma unroll
    for (int e = 0; e < 4; ++e) {
      float ar = 0.f;
#pragma unroll
      for (int j = 0; j < 4; ++j) {
        float v = acc[i][j][e] + bcol[j];
        v = v > 0.f ? v : 0.f;
        ar += v * g2c[j];
      }
      rsum[i][e] = ar;
    }
#pragma unroll
  for (int m = 1; m < 16; m <<= 1)
#pragma unroll
    for (int i = 0; i < 4; ++i)
#pragma unroll
      for (int e = 0; e < 4; ++e) rsum[i][e] += __shfl_xor(rsum[i][e], m, 64);
  if (lc == 0) {
    const int colblk = (cBase + wn) >> 6;  // 0..31
#pragma unroll
    for (int i = 0; i < 4; ++i)
#pragma unroll
      for (int e = 0; e < 4; ++e)
        Gpart[(size_t)(mBase + wm + i * 16 + lr * 4 + e) * 32 + colblk] = rsum[i][e];
  }
}

// ---------- top-P gather + weighted sum + l2norm + residual ----------
__global__ __launch_bounds__(256) void aggregate_k(const float* __restrict__ img_range,
                                                   const float* __restrict__ Gpart,
                                                   const float* __restrict__ gb2,
                                                   const ushort_t* __restrict__ vbf,
                                                   const float* __restrict__ images,
                                                   ushort_t* __restrict__ imgs_out) {
  __shared__ int s_id[5];
  __shared__ float s_w[5];
  __shared__ float sred[4];
  const int row = blockIdx.x;
  const int b = row / 36, k = row - b * 36;
  const int tid = threadIdx.x;
  if (tid < 64) {  // whole wave 0
    float val = (tid < 36) ? img_range[(size_t)row * 36 + tid] : 0.f;
    unsigned long long mask = __ballot(val == 1.0f);
    int myid = k;
    if (tid < 5) {
      // tid-th lowest set bit, else self index k  (== jax stable top_k + where)
      unsigned long long mm = mask;
      for (int p = 0; p < tid; ++p) mm &= (mm - 1);
      myid = mm ? (int)__builtin_ctzll(mm) : k;
      s_id[tid] = myid;
    }
    const float bb = gb2[0];
#pragma unroll
    for (int p = 0; p < 5; ++p) {
      int idp = __shfl(myid, p, 64);
      float v = (tid < 32) ? Gpart[(size_t)(b * 36 + idp) * 32 + tid] : 0.f;
#pragma unroll
      for (int o = 16; o > 0; o >>= 1) v += __shfl_down(v, o, 64);
      if (tid == 0) s_w[p] = 1.f / (1.f + expf(-(v + bb)));
    }
  }
  __syncthreads();
  const int d0 = tid * 8;
  float acc8[8] = {0, 0, 0, 0, 0, 0, 0, 0};
#pragma unroll
  for (int p = 0; p < 5; ++p) {
    uint4 u = *(const uint4*)(vbf + ((size_t)(b * 36 + s_id[p])) * 2048 + d0);
    float wg = s_w[p];
    acc8[0] += wg * bflo(u.x); acc8[1] += wg * bfhi(u.x);
    acc8[2] += wg * bflo(u.y); acc8[3] += wg * bfhi(u.y);
    acc8[4] += wg * bflo(u.z); acc8[5] += wg * bfhi(u.z);
    acc8[6] += wg * bflo(u.w); acc8[7] += wg * bfhi(u.w);
  }
  float ss = 0;
#pragma unroll
  for (int e = 0; e < 8; ++e) ss += acc8[e] * acc8[e];
  float tot = blk_sum(ss, sred);
  float inv = 1.f / (sqrtf(tot) + 1e-8f);
  const float* im = images + (size_t)row * 2048 + d0;
  float4 x0 = *(const float4*)im;
  float4 x1 = *(const float4*)(im + 4);
  float r[8] = {x0.x + acc8[0] * inv, x0.y + acc8[1] * inv, x0.z + acc8[2] * inv,
                x0.w + acc8[3] * inv, x1.x + acc8[4] * inv, x1.y + acc8[5] * inv,
                x1.z + acc8[6] * inv, x1.w + acc8[7] * inv};
  uint4 o;
  o.x = (uint32)f2bf(r[0]) | ((uint32)f2bf(r[1]) << 16);
  o.y = (uint32)f2bf(r[2]) | ((uint32)f2bf(r[3]) << 16);
  o.z = (uint32)f2bf(r[4]) | ((uint32)f2bf(r[5]) << 16);
  o.w = (uint32)f2bf(r[6]) | ((uint32)f2bf(r[7]) << 16);
  *(uint4*)(imgs_out + (size_t)row * 2048 + d0) = o;
}

// ---------- final l2norm over E=1024 ----------
__global__ __launch_bounds__(256) void l2norm_k(const float* __restrict__ emb,
                                                float* __restrict__ out) {
  __shared__ float sred[4];
  size_t base = (size_t)blockIdx.x * 1024 + threadIdx.x * 4;
  float4 x = *(const float4*)(emb + base);
  float tot = blk_sum(x.x * x.x + x.y * x.y + x.z * x.z + x.w * x.w, sred);
  float inv = 1.f / (sqrtf(tot) + 1e-8f);
  float4 o = {x.x * inv, x.y * inv, x.z * inv, x.w * inv};
  *(float4*)(out + base) = o;
}

extern "C" void kernel_launch(void* const* d_in, const int* in_sizes, int n_in,
                              void* d_out, int out_size, void* d_ws, size_t ws_size,
                              hipStream_t stream) {
  (void)in_sizes; (void)n_in; (void)out_size; (void)ws_size;
  const float* images    = (const float*)d_in[0];
  const float* bboxes    = (const float*)d_in[1];
  const float* img_range = (const float*)d_in[2];
  const float* gate_w1   = (const float*)d_in[3];
  const float* gate_b1   = (const float*)d_in[4];
  const float* gate_w2   = (const float*)d_in[5];
  const float* gate_b2   = (const float*)d_in[6];
  const float* node_w1   = (const float*)d_in[7];
  const float* node_b1   = (const float*)d_in[8];
  const float* node_w2   = (const float*)d_in[9];
  const float* node_b2   = (const float*)d_in[10];
  const float* map_w1    = (const float*)d_in[11];
  const float* map_b1    = (const float*)d_in[12];
  const float* map_w2    = (const float*)d_in[13];
  const float* map_b2    = (const float*)d_in[14];

  char* ws = (char*)d_ws;
  size_t off = 0;
  auto take = [&](size_t bytes) {
    char* p = ws + off;
    off += (bytes + 255) & ~(size_t)255;
    return p;
  };
  ushort_t* W1t  = (ushort_t*)take((size_t)4096 * 2112 * 2);  // [gate|node]_w1^T, K-padded
  ushort_t* W2t  = (ushort_t*)take((size_t)2048 * 2048 * 2);  // node_w2^T
  ushort_t* W3t  = (ushort_t*)take((size_t)2048 * 2048 * 2);  // map_w1^T
  ushort_t* W4t  = (ushort_t*)take((size_t)1024 * 2048 * 2);  // map_w2^T
  ushort_t* Abuf = (ushort_t*)take((size_t)9216 * 2112 * 2);  // A (2112) -> imgs (2048)
  ushort_t* Hn   = (ushort_t*)take((size_t)9216 * 2048 * 2);  // node hidden -> H3
  ushort_t* Vbuf = (ushort_t*)take((size_t)9216 * 2048 * 2);  // V bf16 -> Emb fp32
  float*    Gpart = (float*)take((size_t)9216 * 32 * 4);      // gate dot partials
  float*    Emb  = (float*)Vbuf;  // 9216*1024 fp32 == same bytes

  prep_k<<<dim3(64, 72, 7), dim3(32, 8), 0, stream>>>(
      gate_w1, node_w1, node_w2, map_w1, map_w2, images, bboxes,
      W1t, W2t, W3t, W4t, Abuf);

  // Gn: A @ node_w1^T + node_b1, relu -> Hn
  gemm_bt<0><<<dim3(16, 72), 256, 0, stream>>>(Abuf, 2112, W1t + (size_t)2048 * 2112,
                                               2112, Hn, 2048, node_b1);
  // Gg: A @ gate_w1^T -> fused relu+dot partials
  gemm_gate<<<dim3(16, 72), 256, 0, stream>>>(Abuf, 2112, W1t, 2112,
                                              gate_b1, gate_w2, Gpart);
  // G2: Hn @ node_w2^T + node_b2 -> V
  gemm_bt<1><<<dim3(16, 72), 256, 0, stream>>>(Hn, 2048, W2t, 2048, Vbuf, 2048, node_b2);
  aggregate_k<<<9216, 256, 0, stream>>>(img_range, Gpart, gate_b2, Vbuf, images, Abuf);
  // G3: imgs @ map_w1^T + map_b1, relu -> H3 (into Hn)
  gemm_bt<0><<<dim3(16, 72), 256, 0, stream>>>(Abuf, 2048, W3t, 2048, Hn, 2048, map_b1);
  // G4: H3 @ map_w2^T + map_b2 -> Emb fp32 (into Vbuf)
  gemm_bt<2><<<dim3(8, 72), 256, 0, stream>>>(Hn, 2048, W4t, 2048, Emb, 1024, map_b2);
  l2norm_k<<<9216, 256, 0, stream>>>(Emb, (float*)d_out);
}